// Round 3
// baseline (266.322 us; speedup 1.0000x reference)
//
#include <hip/hip_runtime.h>

#define B_ 64
#define C_ 3
#define H_ 384
#define W_ 384
#define HW_ (H_ * W_)

#define TW 32
#define TH 32
#define TILES_X (W_ / TW)          // 12
#define TILES_Y (H_ / TH)          // 12
#define SRCW 48
#define SRCH 48
#define SRCP 49                    // padded LDS row (floats)

__global__ __launch_bounds__(256) void affine_tile_kernel(
    const float* __restrict__ imgs,
    const float* __restrict__ theta,
    float* __restrict__ out)
{
    __shared__ float lds[C_ * SRCH * SRCP];   // 28,224 B

    int bid = blockIdx.x;
    int b = bid / (TILES_X * TILES_Y);
    int r = bid % (TILES_X * TILES_Y);
    int tileY = (r / TILES_X) * TH;
    int tileX = (r % TILES_X) * TW;

    const float* th = theta + b * 6;
    float t00 = th[0], t01 = th[1], t02 = th[2];
    float t10 = th[3], t11 = th[4], t12 = th[5];

    int tx = threadIdx.x & 31;
    int ty = threadIdx.x >> 5;     // 0..7

    // ---- bbox from the 4 tile corners (same fp formula as per-pixel path;
    //      fma rounding is monotone per-argument, so corners bound interior) ----
    float xg0 = (float)tileX - 191.5f;
    float xg1 = (float)(tileX + TW - 1) - 191.5f;
    float yg0 = (float)tileY - 191.5f;
    float yg1 = (float)(tileY + TH - 1) - 191.5f;

    float i0 = fmaf(yg0, t01, t02);
    float i1 = fmaf(yg1, t01, t02);
    float ixa = fmaf(xg0, t00, i0) + 191.5f;
    float ixb = fmaf(xg1, t00, i0) + 191.5f;
    float ixc = fmaf(xg0, t00, i1) + 191.5f;
    float ixd = fmaf(xg1, t00, i1) + 191.5f;
    float ixmin = fminf(fminf(ixa, ixb), fminf(ixc, ixd));
    float ixmax = fmaxf(fmaxf(ixa, ixb), fmaxf(ixc, ixd));

    float j0 = fmaf(yg0, t11, t12);
    float j1 = fmaf(yg1, t11, t12);
    float iya = fmaf(xg0, t10, j0) + 191.5f;
    float iyb = fmaf(xg1, t10, j0) + 191.5f;
    float iyc = fmaf(xg0, t10, j1) + 191.5f;
    float iyd = fmaf(xg1, t10, j1) + 191.5f;
    float iymin = fminf(fminf(iya, iyb), fminf(iyc, iyd));
    float iymax = fmaxf(fmaxf(iya, iyb), fmaxf(iyc, iyd));

    int srcX0 = (int)floorf(ixmin);
    int srcX1 = (int)floorf(ixmax) + 1;
    int srcY0 = (int)floorf(iymin);
    int srcY1 = (int)floorf(iymax) + 1;
    int srcW = srcX1 - srcX0 + 1;
    int srcH = srcY1 - srcY0 + 1;

    const float* bimg = imgs + (size_t)b * (C_ * HW_);
    float* bout = out + (size_t)b * (C_ * HW_);

    if (srcW <= SRCW && srcH <= SRCH) {
        // ---- stage bbox into LDS, zeros for out-of-image (bakes in padding) ----
        for (int c = 0; c < C_; ++c) {
            const float* p = bimg + c * HW_;
            float* l = lds + c * (SRCH * SRCP);
            for (int sy = ty; sy < srcH; sy += 8) {
                int gy = srcY0 + sy;
                bool vy = (gy >= 0) & (gy < H_);
                int gyc = min(max(gy, 0), H_ - 1);
                const float* row = p + gyc * W_;
                for (int sx = tx; sx < srcW; sx += 32) {
                    int gx = srcX0 + sx;
                    bool v = vy & (gx >= 0) & (gx < W_);
                    int gxc = min(max(gx, 0), W_ - 1);
                    float val = row[gxc];
                    l[sy * SRCP + sx] = v ? val : 0.0f;
                }
            }
        }
        __syncthreads();

        // ---- sample: 4 output pixels per thread, all taps from LDS ----
#pragma unroll
        for (int k = 0; k < 4; ++k) {
            int oy = tileY + ty + k * 8;
            int ox = tileX + tx;
            float xg = (float)ox - 191.5f;
            float yg = (float)oy - 191.5f;
            float ix = fmaf(xg, t00, fmaf(yg, t01, t02)) + 191.5f;
            float iy = fmaf(xg, t10, fmaf(yg, t11, t12)) + 191.5f;

            float x0f = floorf(ix);
            float y0f = floorf(iy);
            float wx1 = ix - x0f;
            float wy1 = iy - y0f;
            float wx0 = 1.0f - wx1;
            float wy0 = 1.0f - wy1;
            float w00 = wx0 * wy0, w01 = wx1 * wy0;
            float w10 = wx0 * wy1, w11 = wx1 * wy1;

            int lx = (int)x0f - srcX0;
            int ly = (int)y0f - srcY0;
            int base = ly * SRCP + lx;

#pragma unroll
            for (int c = 0; c < C_; ++c) {
                const float* l = lds + c * (SRCH * SRCP) + base;
                float v00 = l[0];
                float v01 = l[1];
                float v10 = l[SRCP];
                float v11 = l[SRCP + 1];
                float res = fmaf(v00, w00, fmaf(v01, w01,
                            fmaf(v10, w10, v11 * w11)));
                bout[c * HW_ + oy * W_ + ox] = res;
            }
        }
    } else {
        // ---- fallback (≈8-sigma theta draw): direct global gathers ----
#pragma unroll
        for (int k = 0; k < 4; ++k) {
            int oy = tileY + ty + k * 8;
            int ox = tileX + tx;
            float xg = (float)ox - 191.5f;
            float yg = (float)oy - 191.5f;
            float ix = fmaf(xg, t00, fmaf(yg, t01, t02)) + 191.5f;
            float iy = fmaf(xg, t10, fmaf(yg, t11, t12)) + 191.5f;

            float x0f = floorf(ix);
            float y0f = floorf(iy);
            float wx1 = ix - x0f;
            float wy1 = iy - y0f;
            float wx0 = 1.0f - wx1;
            float wy0 = 1.0f - wy1;
            float x1f = x0f + 1.0f;
            float y1f = y0f + 1.0f;

            bool vx0 = (x0f >= 0.0f) && (x0f < (float)W_);
            bool vx1 = (x1f >= 0.0f) && (x1f < (float)W_);
            bool vy0 = (y0f >= 0.0f) && (y0f < (float)H_);
            bool vy1 = (y1f >= 0.0f) && (y1f < (float)H_);

            int x0 = (int)fminf(fmaxf(x0f, 0.0f), (float)(W_ - 1));
            int x1 = (int)fminf(fmaxf(x1f, 0.0f), (float)(W_ - 1));
            int y0 = (int)fminf(fmaxf(y0f, 0.0f), (float)(H_ - 1));
            int y1 = (int)fminf(fmaxf(y1f, 0.0f), (float)(H_ - 1));

            float w00 = wx0 * wy0 * ((vx0 && vy0) ? 1.0f : 0.0f);
            float w01 = wx1 * wy0 * ((vx1 && vy0) ? 1.0f : 0.0f);
            float w10 = wx0 * wy1 * ((vx0 && vy1) ? 1.0f : 0.0f);
            float w11 = wx1 * wy1 * ((vx1 && vy1) ? 1.0f : 0.0f);

            int o00 = y0 * W_ + x0;
            int o01 = y0 * W_ + x1;
            int o10 = y1 * W_ + x0;
            int o11 = y1 * W_ + x1;

#pragma unroll
            for (int c = 0; c < C_; ++c) {
                const float* p = bimg + c * HW_;
                float res = fmaf(p[o00], w00, fmaf(p[o01], w01,
                            fmaf(p[o10], w10, p[o11] * w11)));
                bout[c * HW_ + oy * W_ + ox] = res;
            }
        }
    }
}

extern "C" void kernel_launch(void* const* d_in, const int* in_sizes, int n_in,
                              void* d_out, int out_size, void* d_ws, size_t ws_size,
                              hipStream_t stream) {
    const float* imgs = (const float*)d_in[0];
    const float* theta = (const float*)d_in[1];
    float* out = (float*)d_out;
    int blocks = B_ * TILES_X * TILES_Y;   // 9216
    affine_tile_kernel<<<blocks, 256, 0, stream>>>(imgs, theta, out);
}

// Round 4
// 225.854 us; speedup vs baseline: 1.1792x; 1.1792x over previous
//
#include <hip/hip_runtime.h>

#define B_ 64
#define C_ 3
#define H_ 384
#define W_ 384
#define HW_ (H_ * W_)

// 1 output pixel per thread, 12 gathers issued up-front, XCD-swizzled blocks.
__global__ __launch_bounds__(256) void affine_sample_kernel(
    const float* __restrict__ imgs,
    const float* __restrict__ theta,
    float* __restrict__ out)
{
    // XCD swizzle: consecutive blockIdx are dealt round-robin across 8 XCDs.
    // Give each XCD a contiguous pixel range so the bilinear y-overlap between
    // adjacent output rows stays resident in that XCD's L2 (R1: fetch 190->54MB).
    int nb = gridDim.x;                    // 36,864 (multiple of 8)
    int bid = blockIdx.x;
    int sb = (bid & 7) * (nb >> 3) + (bid >> 3);

    int idx = sb * 256 + threadIdx.x;
    int x = idx % W_;
    int t = idx / W_;
    int y = t % H_;
    int b = t / H_;
    b = __builtin_amdgcn_readfirstlane(b); // block-uniform: 576 blocks per image exactly

    const float* th = theta + b * 6;
    float t00 = th[0], t01 = th[1], t02 = th[2];
    float t10 = th[3], t11 = th[4], t12 = th[5];

    float xg = (float)x - 191.5f;
    float yg = (float)y - 191.5f;

    float ix = fmaf(xg, t00, fmaf(yg, t01, t02)) + 191.5f;
    float iy = fmaf(xg, t10, fmaf(yg, t11, t12)) + 191.5f;

    float x0f = floorf(ix);
    float y0f = floorf(iy);
    float wx1 = ix - x0f;
    float wy1 = iy - y0f;
    float wx0 = 1.0f - wx1;
    float wy0 = 1.0f - wy1;
    float x1f = x0f + 1.0f;
    float y1f = y0f + 1.0f;

    bool vx0 = (x0f >= 0.0f) && (x0f < (float)W_);
    bool vx1 = (x1f >= 0.0f) && (x1f < (float)W_);
    bool vy0 = (y0f >= 0.0f) && (y0f < (float)H_);
    bool vy1 = (y1f >= 0.0f) && (y1f < (float)H_);

    int x0 = (int)fminf(fmaxf(x0f, 0.0f), (float)(W_ - 1));
    int x1 = (int)fminf(fmaxf(x1f, 0.0f), (float)(W_ - 1));
    int y0 = (int)fminf(fmaxf(y0f, 0.0f), (float)(H_ - 1));
    int y1 = (int)fminf(fmaxf(y1f, 0.0f), (float)(H_ - 1));

    float w00 = wx0 * wy0 * ((vx0 && vy0) ? 1.0f : 0.0f);
    float w01 = wx1 * wy0 * ((vx1 && vy0) ? 1.0f : 0.0f);
    float w10 = wx0 * wy1 * ((vx0 && vy1) ? 1.0f : 0.0f);
    float w11 = wx1 * wy1 * ((vx1 && vy1) ? 1.0f : 0.0f);

    int o00 = y0 * W_ + x0;
    int o01 = y0 * W_ + x1;
    int o10 = y1 * W_ + x0;
    int o11 = y1 * W_ + x1;

    const float* bimg = imgs + (size_t)b * (C_ * HW_);
    float* bout = out + (size_t)b * (C_ * HW_) + y * W_ + x;

    // ---- issue ALL 12 gathers before any consumer (max per-thread MLP) ----
    float v[C_][4];
#pragma unroll
    for (int c = 0; c < C_; ++c) {
        const float* p = bimg + c * HW_;
        v[c][0] = p[o00];
        v[c][1] = p[o01];
        v[c][2] = p[o10];
        v[c][3] = p[o11];
    }

#pragma unroll
    for (int c = 0; c < C_; ++c) {
        float r = fmaf(v[c][0], w00, fmaf(v[c][1], w01,
                  fmaf(v[c][2], w10, v[c][3] * w11)));
        bout[c * HW_] = r;
    }
}

extern "C" void kernel_launch(void* const* d_in, const int* in_sizes, int n_in,
                              void* d_out, int out_size, void* d_ws, size_t ws_size,
                              hipStream_t stream) {
    const float* imgs = (const float*)d_in[0];
    const float* theta = (const float*)d_in[1];
    float* out = (float*)d_out;
    int total = B_ * H_ * W_;                 // 9,437,184
    affine_sample_kernel<<<total / 256, 256, 0, stream>>>(imgs, theta, out);
}